// Round 1
// baseline (359.157 us; speedup 1.0000x reference)
//
#include <hip/hip_runtime.h>

#define NE   15000   // edges
#define NVX  8000    // nodes
#define EPAD 15040   // 235*64 padded edge count
#define NT_E 235     // edge tiles of 64

typedef __attribute__((ext_vector_type(8))) short short8;   // 8 x bf16 (4 VGPRs)
typedef __attribute__((ext_vector_type(4))) float f32x4;

static __device__ __forceinline__ unsigned short f2b(float f){
  unsigned int u = __float_as_uint(f);
  u += 0x7fffu + ((u >> 16) & 1u);          // RNE
  return (unsigned short)(u >> 16);
}

// ---------------- P0: f32 -> bf16 bulk convert ----------------
__global__ __launch_bounds__(256) void k_cvt(const float* __restrict__ in,
                                             unsigned short* __restrict__ out, int n){
  int i = (blockIdx.x * 256 + threadIdx.x) * 4;
  if (i >= n) return;
  float4 v = *(const float4*)(in + i);
  ushort4 o;
  o.x = f2b(v.x); o.y = f2b(v.y); o.z = f2b(v.z); o.w = f2b(v.w);
  *(ushort4*)(out + i) = o;
}

// ---------------- P_h1: h1T[h][e] = relu(ea @ W1 + b1), transposed, zero-padded ----
__global__ __launch_bounds__(256) void k_h1(const float* __restrict__ ea,
                                            const float* __restrict__ W1,
                                            const float* __restrict__ b1,
                                            float* __restrict__ h1T){
  __shared__ float sW1[16*128];
  __shared__ float sb1[128];
  int t = threadIdx.x;
  #pragma unroll
  for (int i = 0; i < 8; ++i) sW1[i*256 + t] = W1[i*256 + t];
  if (t < 128) sb1[t] = b1[t];
  __syncthreads();
  int e = blockIdx.x * 64 + (t & 63);
  int hg = t >> 6;                    // wave id -> 32-h group
  bool valid = e < NE;
  int esafe = valid ? e : 0;
  float a[16];
  #pragma unroll
  for (int i = 0; i < 4; ++i){
    float4 v = *(const float4*)(ea + (size_t)esafe*16 + i*4);
    a[i*4+0]=v.x; a[i*4+1]=v.y; a[i*4+2]=v.z; a[i*4+3]=v.w;
  }
  for (int hh = 0; hh < 32; ++hh){
    int h = hg*32 + hh;
    float s = sb1[h];
    #pragma unroll
    for (int k = 0; k < 16; ++k) s = fmaf(a[k], sW1[k*128 + h], s);
    s = fmaxf(s, 0.f);
    h1T[(size_t)h*EPAD + e] = valid ? s : 0.f;   // coalesced along e
  }
}

// ---------------- P1: transpose + bf16 + XOR-swizzle weight blocks ----------------
// Each block b produces a 32KB block T[o][k] (bf16) with byte^((o&7)<<4) swizzle baked in.
// b in [0,127]: W2 block h ; b==128: b2 ; b==129..132: W0,root,Wm[:128],Wm[128:]
__global__ __launch_bounds__(256) void k_wt(const float* __restrict__ W2,
                                            const float* __restrict__ b2,
                                            const float* __restrict__ W0,
                                            const float* __restrict__ root,
                                            const float* __restrict__ Wm,
                                            unsigned short* __restrict__ W2T,
                                            unsigned short* __restrict__ sWt){
  int b = blockIdx.x;
  const float* src;
  unsigned short* out;
  if (b < 128)      { src = W2 + (size_t)b*16384; out = W2T + (size_t)b*16384; }
  else if (b == 128){ src = b2;                   out = W2T + (size_t)128*16384; }
  else {
    int s = b - 129;
    out = sWt + (size_t)s*16384;
    src = (s==0) ? W0 : (s==1) ? root : (s==2) ? Wm : (Wm + 128*128);
  }
  int t = threadIdx.x;
  int o = t & 127, half = t >> 7;
  for (int it = 0; it < 8; ++it){
    int d0 = half*64 + it*8;
    unsigned int pk[4];
    #pragma unroll
    for (int j = 0; j < 4; ++j){
      float v0 = src[(size_t)(d0 + 2*j    )*128 + o];   // coalesced across lanes (consecutive o)
      float v1 = src[(size_t)(d0 + 2*j + 1)*128 + o];
      pk[j] = (unsigned int)f2b(v0) | ((unsigned int)f2b(v1) << 16);
    }
    unsigned int off = (unsigned int)(o*256 + d0*2) ^ (((unsigned int)(o & 7)) << 4);
    *(uint4*)((char*)out + off) = make_uint4(pk[0], pk[1], pk[2], pk[3]);
  }
}

// ---------------- big edge GEMM: msg = sum_h h1[e,h]*(xs@W2_h)  (+b2 block), scatter-add ---
// grid = 2*NT_E : blockIdx = (tile<<1)|parity ; parity splits h to double grid occupancy.
__global__ __launch_bounds__(256,2) void k_big(const unsigned short* __restrict__ outcur,
                                               const unsigned short* __restrict__ W2T,
                                               const float* __restrict__ h1T,
                                               const int* __restrict__ eidx,
                                               float* __restrict__ agg){
  __shared__ __align__(16) unsigned short sX[64*128];   // gathered xs rows (bf16, linear)
  __shared__ __align__(16) float          sH[64*64];    // h1T parity rows [hh][row]
  __shared__ __align__(16) unsigned short sW[128*128];  // W2T_h (swizzled layout)
  int t = threadIdx.x, l = t & 63, w = t >> 6;
  int tile = blockIdx.x >> 1, par = blockIdx.x & 1;
  int e0 = tile * 64;
  { // gather xs rows
    int r = t >> 2, q = t & 3;
    int e = e0 + r;
    int srow = eidx[e < NE ? e : NE-1];
    const uint4* gp = (const uint4*)((const char*)outcur + (size_t)srow*256 + q*64);
    uint4* lp = (uint4*)((char*)sX + r*256 + q*64);
    #pragma unroll
    for (int i = 0; i < 4; ++i) lp[i] = gp[i];
  }
  { // stage h1T parity rows: 64 rows x 64 f32
    int hh = t >> 2, q = t & 3;
    int h = par + hh*2;
    const uint4* gp = (const uint4*)((const char*)h1T + ((size_t)h*EPAD + e0)*4 + q*64);
    uint4* lp = (uint4*)((char*)sH + hh*256 + q*64);
    #pragma unroll
    for (int i = 0; i < 4; ++i) lp[i] = gp[i];
  }
  __syncthreads();
  // A fragments: xs rows, persistent in registers for all h
  short8 af[4][4];
  #pragma unroll
  for (int mf = 0; mf < 4; ++mf)
    #pragma unroll
    for (int kf = 0; kf < 4; ++kf)
      af[mf][kf] = *(const short8*)((const char*)sX + (mf*16 + (l & 15))*256 + kf*64 + ((l >> 4)*16));
  f32x4 acc[4][2];
  #pragma unroll
  for (int mf = 0; mf < 4; ++mf)
    #pragma unroll
    for (int nf = 0; nf < 2; ++nf)
      acc[mf][nf] = (f32x4){0.f,0.f,0.f,0.f};
  const f32x4 zf = (f32x4){0.f,0.f,0.f,0.f};
  int nh = (par == 0) ? 65 : 64;                 // parity 0 also does the b2 block (h=128)
  for (int hh = 0; hh < nh; ++hh){
    int h = (hh < 64) ? (par + hh*2) : 128;
    __syncthreads();                             // previous iter done reading sW
    { // stage W2T block h (32KB, pre-swizzled in global -> linear copy)
      const uint4* gp = (const uint4*)((const char*)W2T + (size_t)h*32768);
      uint4* lp = (uint4*)sW;
      #pragma unroll
      for (int i = 0; i < 8; ++i) lp[i*256 + t] = gp[i*256 + t];
    }
    __syncthreads();
    f32x4 hv[4];
    if (hh < 64){
      #pragma unroll
      for (int mf = 0; mf < 4; ++mf)
        hv[mf] = *(const f32x4*)((const char*)sH + hh*256 + mf*64 + ((l >> 4)*16));
    } else {
      #pragma unroll
      for (int mf = 0; mf < 4; ++mf){
        int rb = e0 + mf*16 + ((l >> 4) << 2);
        #pragma unroll
        for (int j = 0; j < 4; ++j) hv[mf][j] = (rb + j < NE) ? 1.f : 0.f;
      }
    }
    #pragma unroll
    for (int nf = 0; nf < 2; ++nf){
      int col = w*32 + nf*16 + (l & 15);
      unsigned int swz = ((unsigned int)(col & 7)) << 4;
      f32x4 Y[4];
      #pragma unroll
      for (int kf = 0; kf < 4; ++kf){
        short8 bfr = *(const short8*)((const char*)sW +
                        (((unsigned int)(col*256 + kf*64 + ((l >> 4)*16))) ^ swz));
        #pragma unroll
        for (int mf = 0; mf < 4; ++mf)
          Y[mf] = __builtin_amdgcn_mfma_f32_16x16x32_bf16(af[mf][kf], bfr,
                    (kf == 0) ? zf : Y[mf], 0, 0, 0);
      }
      #pragma unroll
      for (int mf = 0; mf < 4; ++mf)
        #pragma unroll
        for (int j = 0; j < 4; ++j)
          acc[mf][nf][j] = fmaf(hv[mf][j], Y[mf][j], acc[mf][nf][j]);
    }
  }
  // fused segment_sum: atomic scatter to agg[dst]
  #pragma unroll
  for (int mf = 0; mf < 4; ++mf){
    #pragma unroll
    for (int j = 0; j < 4; ++j){
      int e = e0 + mf*16 + ((l >> 4) << 2) + j;
      int dst = (e < NE) ? eidx[NE + e] : 0;     // pad rows add 0.0
      float* ap = agg + (size_t)dst*128;
      #pragma unroll
      for (int nf = 0; nf < 2; ++nf){
        int col = w*32 + nf*16 + (l & 15);
        atomicAdd(ap + col, acc[mf][nf][j]);
      }
    }
  }
}

// ---------------- small GEMM: C = act( Aa@Wa [+ Ab@Wb] [+ addin] + bias ) ----------------
__global__ __launch_bounds__(256,2) void k_gsm(const unsigned short* __restrict__ Aa,
                                               const unsigned short* __restrict__ Wa,
                                               const unsigned short* __restrict__ Ab,
                                               const unsigned short* __restrict__ Wb,
                                               const float* __restrict__ addin,
                                               const float* __restrict__ bias,
                                               int do_relu,
                                               unsigned short* __restrict__ outb,
                                               float* __restrict__ outf){
  __shared__ __align__(16) unsigned short sA[64*128];
  __shared__ __align__(16) unsigned short sW[128*128];
  int t = threadIdx.x, l = t & 63, w = t >> 6;
  int r0 = blockIdx.x * 64;
  f32x4 acc[4][2];
  #pragma unroll
  for (int mf = 0; mf < 4; ++mf)
    #pragma unroll
    for (int nf = 0; nf < 2; ++nf)
      acc[mf][nf] = (f32x4){0.f,0.f,0.f,0.f};
  const unsigned short* A = Aa;
  const unsigned short* W = Wa;
  for (int pass = 0; pass < 2; ++pass){
    if (pass == 1){
      if (Ab == nullptr) break;
      A = Ab; W = Wb;
      __syncthreads();                            // pass0 done with sA/sW
    }
    {
      const uint4* gp = (const uint4*)((const char*)A + (size_t)r0*256);
      uint4* lp = (uint4*)sA;
      #pragma unroll
      for (int i = 0; i < 4; ++i) lp[i*256 + t] = gp[i*256 + t];
      const uint4* gw = (const uint4*)W;
      uint4* lw = (uint4*)sW;
      #pragma unroll
      for (int i = 0; i < 8; ++i) lw[i*256 + t] = gw[i*256 + t];
    }
    __syncthreads();
    short8 af[4][4];
    #pragma unroll
    for (int mf = 0; mf < 4; ++mf)
      #pragma unroll
      for (int kf = 0; kf < 4; ++kf)
        af[mf][kf] = *(const short8*)((const char*)sA + (mf*16 + (l & 15))*256 + kf*64 + ((l >> 4)*16));
    #pragma unroll
    for (int nf = 0; nf < 2; ++nf){
      int col = w*32 + nf*16 + (l & 15);
      unsigned int swz = ((unsigned int)(col & 7)) << 4;
      #pragma unroll
      for (int kf = 0; kf < 4; ++kf){
        short8 bfr = *(const short8*)((const char*)sW +
                        (((unsigned int)(col*256 + kf*64 + ((l >> 4)*16))) ^ swz));
        #pragma unroll
        for (int mf = 0; mf < 4; ++mf)
          acc[mf][nf] = __builtin_amdgcn_mfma_f32_16x16x32_bf16(af[mf][kf], bfr, acc[mf][nf], 0, 0, 0);
      }
    }
  }
  #pragma unroll
  for (int mf = 0; mf < 4; ++mf){
    #pragma unroll
    for (int nf = 0; nf < 2; ++nf){
      #pragma unroll
      for (int j = 0; j < 4; ++j){
        int r = r0 + mf*16 + ((l >> 4) << 2) + j;
        int c = w*32 + nf*16 + (l & 15);
        float v = acc[mf][nf][j];
        if (addin) v += addin[(size_t)r*128 + c];
        v += bias[c];
        if (do_relu) v = fmaxf(v, 0.f);
        if (outb) outb[(size_t)r*128 + c] = f2b(v);
        if (outf) outf[(size_t)r*128 + c] = v;
      }
    }
  }
}

extern "C" void kernel_launch(void* const* d_in, const int* in_sizes, int n_in,
                              void* d_out, int out_size, void* d_ws, size_t ws_size,
                              hipStream_t stream){
  (void)in_sizes; (void)n_in; (void)out_size; (void)ws_size;
  const float* x    = (const float*)d_in[0];
  const float* ea   = (const float*)d_in[1];
  const float* W0   = (const float*)d_in[2];
  const float* b0   = (const float*)d_in[3];
  const float* W1   = (const float*)d_in[4];
  const float* b1   = (const float*)d_in[5];
  const float* W2   = (const float*)d_in[6];
  const float* b2   = (const float*)d_in[7];
  const float* root = (const float*)d_in[8];
  const float* bias = (const float*)d_in[9];
  const float* Wm   = (const float*)d_in[10];
  const float* bm   = (const float*)d_in[11];
  const int*   eidx = (const int*)d_in[12];

  char* p = (char*)d_ws;
  unsigned short* W2T = (unsigned short*)p; p += (size_t)129*32768;   // 4.23 MB (swizzled bf16)
  unsigned short* sWt = (unsigned short*)p; p += (size_t)4*32768;     // W0T,rootT,WmAT,WmBT
  float*          h1T = (float*)p;          p += (size_t)128*EPAD*4;  // 7.70 MB
  unsigned short* xb  = (unsigned short*)p; p += (size_t)NVX*128*2;
  unsigned short* oA  = (unsigned short*)p; p += (size_t)NVX*128*2;
  unsigned short* oB  = (unsigned short*)p; p += (size_t)NVX*128*2;
  unsigned short* mB  = (unsigned short*)p; p += (size_t)NVX*128*2;
  float*          agg = (float*)p;          p += (size_t)NVX*128*4;   // total ~24.3 MB

  k_cvt<<<1000, 256, 0, stream>>>(x, xb, NVX*128);
  k_h1 <<<NT_E, 256, 0, stream>>>(ea, W1, b1, h1T);
  k_wt <<<133,  256, 0, stream>>>(W2, b2, W0, root, Wm, W2T, sWt);
  // lin0: out = relu(x @ W0 + b0)
  k_gsm<<<125, 256, 0, stream>>>(xb, sWt + 0*16384,
                                 (const unsigned short*)nullptr, (const unsigned short*)nullptr,
                                 (const float*)nullptr, b0, 1, oA, (float*)nullptr);
  unsigned short* cur = oA;
  unsigned short* nxt = oB;
  for (int s = 0; s < 3; ++s){
    hipMemsetAsync(agg, 0, (size_t)NVX*128*4, stream);
    k_big<<<2*NT_E, 256, 0, stream>>>(cur, W2T, h1T, eidx, agg);
    // m = relu(agg + out@root + bias)
    k_gsm<<<125, 256, 0, stream>>>(cur, sWt + 1*16384,
                                   (const unsigned short*)nullptr, (const unsigned short*)nullptr,
                                   agg, bias, 1, mB, (float*)nullptr);
    if (s < 2){
      // out_next = m@Wm[:128] + out@Wm[128:] + bm
      k_gsm<<<125, 256, 0, stream>>>(mB, sWt + 2*16384, cur, sWt + 3*16384,
                                     (const float*)nullptr, bm, 0, nxt, (float*)nullptr);
    } else {
      // final: d_out = m@Wm[:128] + out@Wm[128:] + bm + x
      k_gsm<<<125, 256, 0, stream>>>(mB, sWt + 2*16384, cur, sWt + 3*16384,
                                     x, bm, 0, (unsigned short*)nullptr, (float*)d_out);
    }
    unsigned short* tsw = cur; cur = nxt; nxt = tsw;
  }
}